// Round 7
// baseline (270.499 us; speedup 1.0000x reference)
//
#include <hip/hip_runtime.h>

#define NCOMP 8
#define NCONT 56
#define NCAT 8
#define NU 100
#define SEPC 1e-3f
#define T1F 10.0f

// One combined weight array: per feature f (0..55), 35 float4 "roles":
//  role 2c+t      : Wh comp c, k=8t..8t+7   (16 roles)
//  role 16+2c+t   : Wv comp c, k=8t..8t+7   (16 roles)
//  role 32+t      : Wic,       k=8t..8t+7   (2 roles)
//  role 34        : pad  (stride 35 float4 = 140 dwords -> balanced banks)
#define FSTRIDE 35
#define WS_NW4 2048            // float4 count of packed weight image (padded)
#define WS_BIAS_OFF 32768      // byte offset of biases inside workspace

typedef __fp16 f16x2 __attribute__((ext_vector_type(2)));
typedef _Float16 h2arith __attribute__((ext_vector_type(2)));

union H8 { f16x2 h2[4]; float4 f4; };

__device__ __forceinline__ float sp(float x) {
    // softplus = ln2 * log2(1 + 2^(x*log2e)) via v_exp_f32/v_log_f32
    return 0.69314718f * __builtin_amdgcn_logf(1.0f + __builtin_amdgcn_exp2f(x * 1.44269504f));
}

__device__ __forceinline__ f16x2 pkrtz(float a, float b) {
    return __builtin_amdgcn_cvt_pkrtz(a, b);
}

__device__ __forceinline__ float fdot2(f16x2 a, f16x2 b, float c) {
    return __builtin_amdgcn_fdot2(a, b, c, false);
}

__device__ __forceinline__ h2arith h2shfl_xor(h2arith v, int off) {
    int i = __builtin_bit_cast(int, v);
    i = __shfl_xor(i, off, 64);
    return __builtin_bit_cast(h2arith, i);
}

// One continuous-feature accumulation against LDS weights (LDS-served beats
// L2-served by ~16 us/dispatch — round-4 evidence).
__device__ __forceinline__ void acc_cont(const float4* __restrict__ pw,
                                         float4 a0, float4 a1, float4 a2, float4 a3,
                                         float* sh, float* sw, float& ic) {
    f16x2 ba[8];
    ba[0] = pkrtz(a0.x, a0.y); ba[1] = pkrtz(a0.z, a0.w);
    ba[2] = pkrtz(a1.x, a1.y); ba[3] = pkrtz(a1.z, a1.w);
    ba[4] = pkrtz(a2.x, a2.y); ba[5] = pkrtz(a2.z, a2.w);
    ba[6] = pkrtz(a3.x, a3.y); ba[7] = pkrtz(a3.z, a3.w);
#pragma unroll
    for (int c = 0; c < NCOMP; ++c) {
        H8 u0, u1, v0, v1;
        u0.f4 = pw[2 * c];      u1.f4 = pw[2 * c + 1];
        v0.f4 = pw[16 + 2 * c]; v1.f4 = pw[17 + 2 * c];
        float hA = 0.0f, vA = 0.0f;
#pragma unroll
        for (int p = 0; p < 4; ++p) {
            hA = fdot2(ba[p], u0.h2[p], hA);
            vA = fdot2(ba[p], v0.h2[p], vA);
        }
#pragma unroll
        for (int p = 0; p < 4; ++p) {
            hA = fdot2(ba[4 + p], u1.h2[p], hA);
            vA = fdot2(ba[4 + p], v1.h2[p], vA);
        }
        sh[c] += sp(hA);
        sw[c] += sp(vA);
    }
    H8 i0, i1;
    i0.f4 = pw[32]; i1.f4 = pw[33];
    float iA = 0.0f;
#pragma unroll
    for (int p = 0; p < 4; ++p) iA = fdot2(ba[p], i0.h2[p], iA);
#pragma unroll
    for (int p = 0; p < 4; ++p) iA = fdot2(ba[4 + p], i1.h2[p], iA);
    ic += iA;   // IC has no softplus
}

// ---- prep: pack fp16 weights + softplus'd biases into workspace (once) ----
__global__ __launch_bounds__(512) void prep_kernel(
    const float* __restrict__ Wh, const float* __restrict__ Wv,
    const float* __restrict__ Wic, const float* __restrict__ bh,
    const float* __restrict__ bv, const float* __restrict__ bic,
    float4* __restrict__ ws)
{
    const int id = blockIdx.x * 512 + threadIdx.x;   // 0..2047 (grid=4)
    const int i  = id / FSTRIDE;
    const int rr = id - i * FSTRIDE;
    H8 u;
    u.f4 = make_float4(0.f, 0.f, 0.f, 0.f);
    if (i < NCONT && rr < 34) {
        if (rr < 32) {
            const int c = (rr & 15) >> 1;
            const int t = rr & 1;
            const float* W  = (rr < 16) ? Wh : Wv;
            const float* gp = W + (size_t)(8 * t) * 448 + i * 8 + c;
#pragma unroll
            for (int p = 0; p < 4; ++p)
                u.h2[p] = pkrtz(gp[(2 * p) * 448], gp[(2 * p + 1) * 448]);
        } else {
            const int t = rr - 32;
            const float* gp = Wic + (size_t)(8 * t) * 56 + i;
#pragma unroll
            for (int p = 0; p < 4; ++p)
                u.h2[p] = pkrtz(gp[(2 * p) * 56], gp[(2 * p + 1) * 56]);
        }
    }
    ws[id] = u.f4;
    if (id < NCOMP) {
        float2* b2 = (float2*)((char*)ws + WS_BIAS_OFF);
        b2[id] = make_float2(sp(bh[id]), sp(bv[id]));
    }
    if (id == NCOMP) {
        *((float*)((char*)ws + WS_BIAS_OFF + 64)) = bic[0];
    }
}

// Persistent-block design: 1024 blocks x 8 waves; each wave owns ONE row per
// chunk-iteration (lane = feature: 0..55 cont, 56..63 cat), 4 iterations, NO
// barrier inside the loop -> waves de-phase naturally (anti-convoy).  Scan is
// 4 loads/wave consumed immediately (no live-across-acc registers: the
// round-1/5 spill killer).  (512,4): VGPR cap 128, est. live peak ~100.
__global__ __launch_bounds__(512, 4) void tpm_kernel(
    const float* __restrict__ B, const float* __restrict__ Bcat,
    const float* __restrict__ Whc, const float* __restrict__ Wvc,
    const float* __restrict__ Wicc, const float4* __restrict__ ws,
    float* __restrict__ out)
{
    __shared__ float4 sW[WS_NW4];           // 32768 B, packed f16 weights
    __shared__ float2 sBias[NCOMP];         // (sp(bh), sp(bv))
    __shared__ float  sBic;
    __shared__ int    sCode[8][NCAT];       // [wave][cat feature], current row

    const int tid  = threadIdx.x;
    const int lane = tid & 63;
    const int widx = tid >> 6;              // 0..7

    // ---- stage weights once; the ONLY barrier in the kernel ----
#pragma unroll
    for (int k = 0; k < 4; ++k) sW[tid + k * 512] = ws[tid + k * 512];
    if (tid < NCOMP) sBias[tid] = ((const float2*)((const char*)ws + WS_BIAS_OFF))[tid];
    if (tid == NCOMP) sBic = *((const float*)((const char*)ws + WS_BIAS_OFF + 64));
    __syncthreads();

#pragma unroll 1
    for (int it = 0; it < 4; ++it) {
        const int row = (it << 13) + (blockIdx.x << 3) + widx;   // exact cover
        const float* browp = B + (size_t)row * 896;

        // ---- B data for this lane's feature (issued first, used ~1k cy later)
        float4 b0, b1, b2, b3;
        if (lane < NCONT) {
            const float4* p = (const float4*)(browp + lane * 16);
            b0 = p[0]; b1 = p[1]; b2 = p[2]; b3 = p[3];
        }

        // ---- one-hot scan of OWN row: 200 float4 over 64 lanes = 4 iters ----
        {
            const float4* pc = (const float4*)(Bcat + (size_t)row * 800);
#pragma unroll
            for (int k = 0; k < 4; ++k) {
                int idx = (k << 6) + lane;
                if (k < 3 || idx < 200) {
                    float4 q = pc[idx];
                    float n = (float)(4 * idx);
                    float sc = q.x * (n + 1.0f) + q.y * (n + 2.0f)
                             + q.z * (n + 3.0f) + q.w * (n + 4.0f);
                    if (sc > 0.5f) {
                        int p = (int)sc - 1;          // element within row's 800
                        int f = p / NU;
                        sCode[widx][f] = p - f * NU;
                    }
                }
            }
        }
        __threadfence_block();              // ds-write -> ds-read order, same wave

        // ---- cat gather (8 lanes), issued BEFORE cont compute so its latency
        //      hides under the ~1400 cy fdot2 block (round-2-proven pattern) ----
        float4 p3a, p3b, p3c, p3d;
        float p3ic = 0.0f;
        if (lane >= NCONT) {
            int fi = lane - NCONT;
            int cc = sCode[widx][fi];
            int gA = fi * NU + cc;
            const float4* qh = (const float4*)(Whc + gA * 8);
            const float4* qv = (const float4*)(Wvc + gA * 8);
            p3a = qh[0]; p3b = qh[1]; p3c = qv[0]; p3d = qv[1];
            p3ic = Wicc[gA];
        }

        // ---- accumulators: 17 channels for this lane's feature ----
        float sh[NCOMP], sw[NCOMP];
        float ic = 0.0f;
#pragma unroll
        for (int c = 0; c < NCOMP; ++c) { sh[c] = sw[c] = 0.0f; }

        if (lane < NCONT) {
            acc_cont(sW + lane * FSTRIDE, b0, b1, b2, b3, sh, sw, ic);
        } else {
            sh[0] += sp(p3a.x); sh[1] += sp(p3a.y); sh[2] += sp(p3a.z); sh[3] += sp(p3a.w);
            sh[4] += sp(p3b.x); sh[5] += sp(p3b.y); sh[6] += sp(p3b.z); sh[7] += sp(p3b.w);
            sw[0] += sp(p3c.x); sw[1] += sp(p3c.y); sw[2] += sp(p3c.z); sw[3] += sp(p3c.w);
            sw[4] += sp(p3d.x); sw[5] += sp(p3d.y); sw[6] += sp(p3d.z); sw[7] += sp(p3d.w);
            ic += p3ic;
        }

        // ---- pack and 6-step butterfly across the full wave (64 features) ----
        h2arith hw[NCOMP];
#pragma unroll
        for (int c = 0; c < NCOMP; ++c)
            hw[c] = __builtin_bit_cast(h2arith, pkrtz(sh[c], sw[c]));
#pragma unroll
        for (int off = 32; off >= 1; off >>= 1) {
#pragma unroll
            for (int c = 0; c < NCOMP; ++c)
                hw[c] = hw[c] + h2shfl_xor(hw[c], off);
            ic += __shfl_xor(ic, off, 64);
        }

        // ---- lanes 0..8 emit (t, x) for this row ----
        if (lane < 9) {
            int m = (lane == 8) ? 7 : lane;
            float tj = SEPC * (float)lane;
            float xj = ic + sBic;
#pragma unroll
            for (int c = 0; c < NCOMP; ++c) {
                float2 bb2 = sBias[c];
                if (c < m) tj += (float)hw[c][0] + bb2.x;
                if (c < lane) {
                    float vv = (float)hw[c][1] + bb2.y;
                    xj += (c & 1) ? -vv : vv;
                }
            }
            if (lane == 8) tj = fmaxf(tj, T1F);
            float2 o; o.x = tj; o.y = xj;
            ((float2*)out)[(size_t)row * 9 + lane] = o;
        }
    }
}

extern "C" void kernel_launch(void* const* d_in, const int* in_sizes, int n_in,
                              void* d_out, int out_size, void* d_ws, size_t ws_size,
                              hipStream_t stream) {
    (void)in_sizes; (void)n_in; (void)out_size; (void)ws_size;
    const float* B    = (const float*)d_in[0];
    const float* Bcat = (const float*)d_in[1];
    const float* Wh   = (const float*)d_in[2];
    const float* Whc  = (const float*)d_in[3];
    const float* bh   = (const float*)d_in[4];
    const float* Wv   = (const float*)d_in[5];
    const float* Wvc  = (const float*)d_in[6];
    const float* bv   = (const float*)d_in[7];
    const float* Wic  = (const float*)d_in[8];
    const float* Wicc = (const float*)d_in[9];
    const float* bic  = (const float*)d_in[10];
    float* out = (float*)d_out;
    float4* ws = (float4*)d_ws;   // needs 32836 B: 32 KB weight image + biases

    // pack weights once (tiny), then the persistent-block streaming kernel
    hipLaunchKernelGGL(prep_kernel, dim3(4), dim3(512), 0, stream,
                       Wh, Wv, Wic, bh, bv, bic, ws);
    // 1024 blocks x 8 waves; each wave: 4 rows over 4 chunk-iterations
    hipLaunchKernelGGL(tpm_kernel, dim3(1024), dim3(512), 0, stream,
                       B, Bcat, Whc, Wvc, Wicc, ws, out);
}